// Round 12
// baseline (575.285 us; speedup 1.0000x reference)
//
#include <hip/hip_runtime.h>

namespace {

constexpr int kS = 1024;
constexpr int kD = 64;
constexpr int kH = 128;

typedef __attribute__((ext_vector_type(2))) _Float16 half2v;
typedef __attribute__((ext_vector_type(4))) float f32x4;
typedef __attribute__((ext_vector_type(8))) _Float16 half8;

__device__ __forceinline__ float fdot2(unsigned w, unsigned h, float acc) {
#if __has_builtin(__builtin_amdgcn_fdot2)
  return __builtin_amdgcn_fdot2(__builtin_bit_cast(half2v, w),
                                __builtin_bit_cast(half2v, h), acc, false);
#else
  float d;
  asm("v_dot2_f32_f16 %0, %1, %2, %3" : "=v"(d) : "v"(w), "v"(h), "v"(acc));
  return d;
#endif
}

// broadcast lane k's packed h-dword to all lanes, result in VGPR
__device__ __forceinline__ unsigned bcast(unsigned v, int k) {
  return (unsigned)__builtin_amdgcn_ds_bpermute(4 * k, (int)v);
}

// RNE f16 pack (cvt_pkrtz is RTZ -> systematic shrink bias over 1024 steps)
__device__ __forceinline__ unsigned pk16(float a, float b) {
  half2v h;
  h.x = (_Float16)a;
  h.y = (_Float16)b;
  return __builtin_bit_cast(unsigned, h);
}

__device__ __forceinline__ half8 to_h8(float4 a, float4 c) {
  half8 h;
  h[0] = (_Float16)a.x; h[1] = (_Float16)a.y; h[2] = (_Float16)a.z; h[3] = (_Float16)a.w;
  h[4] = (_Float16)c.x; h[5] = (_Float16)c.y; h[6] = (_Float16)c.z; h[7] = (_Float16)c.w;
  return h;
}

__device__ __forceinline__ float fast_tanh(float x) {
#if __has_builtin(__builtin_amdgcn_fmed3f)
  x = __builtin_amdgcn_fmed3f(x, -15.f, 15.f);  // single-instr clamp
#else
  x = fminf(fmaxf(x, -15.f), 15.f);
#endif
  float e = __expf(2.f * x);
  return (e - 1.f) * __builtin_amdgcn_rcpf(e + 1.f);
}

#if __has_builtin(__builtin_amdgcn_mov_dpp)
__device__ __forceinline__ float lane_xor1(float v) {
  return __int_as_float(__builtin_amdgcn_mov_dpp(__float_as_int(v), 0xB1, 0xF, 0xF, true));
}
#else
__device__ __forceinline__ float lane_xor1(float v) {
  return __int_as_float(__builtin_amdgcn_ds_swizzle(__float_as_int(v), 0x041F));
}
#endif

// Bank-conflict swizzle for the [32][64]-f32 instage tile (rule #21: linear
// LDS dest + inverse-swizzled global SOURCE + swizzled reads). Row r's dwords
// are XORed by (r&7)<<2 (bits 2-4, preserves 16B alignment, bijective per row).
// Takes buildx's 64-lane b128 column reads from 16-way conflict to the 8-cycle
// wave64 floor.
__device__ __forceinline__ int swz(int dw) {
  return dw ^ (((dw >> 6) & 7) << 2);
}

// async global->LDS, source pre-swizzled so LDS holds the swizzled tile.
// dst dwords [k*256 + L*4 .. +3] <- global dwords swz(k*256 + L*4) .. +3.
__device__ __forceinline__ void stage_chunk_sw(const char* g, unsigned* lds, int L) {
#pragma unroll
  for (int k = 0; k < 8; ++k) {
    const int d0 = k * 256 + L * 4;
    __builtin_amdgcn_global_load_lds(
        (const __attribute__((address_space(1))) void*)(g + swz(d0) * 4),
        (__attribute__((address_space(3))) void*)(lds + k * 256), 16, 0, 0);
  }
}

// =====================  Fused BiRNN: xproj-on-matrix-pipe + R7 recurrence  ======
// 512 blocks x 64 threads (ONE wave): dir = blockIdx>>8, b = blockIdx&255.
// Per 32-step chunk: DMA the raw inputs chunk (32 t x 64 D f32 = 8 KB, swizzled
// source), compute x = inputs*Wih^T via 32 mfma_f32_16x16x32_f16 (verified xproj
// fragment layout), pack C quads to xcomp (packed-f16, 68-dw rows). buildx for
// chunk c+1 is issued BEFORE chunk c's fc drain so the MFMA drain overlaps the
// drain's VALU/LDS work. Step loop = R7 core (64 bpermute + 128 fdot2), bias
// folded at x-read. No xp workspace, no second kernel.
__global__ __launch_bounds__(64, 1) void birnn_fused_kernel(
    const float* __restrict__ inputs,
    const float* __restrict__ Wih_fw, const float* __restrict__ bih_fw,
    const float* __restrict__ bhh_fw,
    const float* __restrict__ Wih_bw, const float* __restrict__ bih_bw,
    const float* __restrict__ bhh_bw,
    const float* __restrict__ Whh_fw, const float* __restrict__ Whh_bw,
    const float* __restrict__ fcW, const float* __restrict__ fcb,
    float* __restrict__ out) {
  const int dir = blockIdx.x >> 8;
  const int b = blockIdx.x & 255;
  const int L = threadIdx.x;
  const int n16 = L & 15;
  const int q = L >> 4;

  __shared__ float instage[2][2048];  // two staged 8 KB inputs chunks (f32, swizzled)
  __shared__ unsigned xcomp[32 * 68]; // computed x, packed f16 pairs, 68-dw rows
  __shared__ unsigned jrn[32 * 68];   // h ring + fc journal
  __shared__ unsigned fcwl[64];       // fc weights, packed f16 pairs
  __shared__ float outbuf[kS];

  const float* __restrict__ Whh = dir ? Whh_bw : Whh_fw;
  const float* __restrict__ Wih = dir ? Wih_bw : Wih_fw;
  const float* __restrict__ bihd = dir ? bih_bw : bih_fw;
  const float* __restrict__ bhhd = dir ? bhh_bw : bhh_fw;

  // ---- Whh weights: rows j0=2L, j1=2L+1 -> 128 packed-f16 dwords ----
  unsigned w0[64], w1[64];
  {
    const float* r0 = Whh + (size_t)(2 * L) * kH;
    const float* r1 = Whh + (size_t)(2 * L + 1) * kH;
#pragma unroll
    for (int k = 0; k < 64; ++k) {
      w0[k] = pk16(r0[2 * k], r0[2 * k + 1]);
      w1[k] = pk16(r1[2 * k], r1[2 * k + 1]);
    }
  }
  // ---- Wih A-fragments (persistent): AW[m][tk] ----
  half8 AW[8][2];
#pragma unroll
  for (int m = 0; m < 8; ++m) {
#pragma unroll
    for (int tk = 0; tk < 2; ++tk) {
      const float* src = Wih + (size_t)(16 * m + n16) * kD + 32 * tk + 8 * q;
      AW[m][tk] = to_h8(*(const float4*)src, *(const float4*)(src + 4));
    }
  }
  const float bj0 = bihd[2 * L] + bhhd[2 * L];
  const float bj1 = bihd[2 * L + 1] + bhhd[2 * L + 1];
  fcwl[L] = pk16(fcW[dir * kH + 2 * L], fcW[dir * kH + 2 * L + 1]);

  unsigned hcur = 0;  // h_{-1} = 0 (lane-local packed pair)
  const f32x4 zeroq = {0.f, 0.f, 0.f, 0.f};

  // ---- x-projection for one staged chunk: 4 B-frags (swizzled reads), 32 MFMA,
  //      16 b64 writes into xcomp ----
  auto buildx = [&](const float* stg) {
    half8 Bf[2][2];
#pragma unroll
    for (int n = 0; n < 2; ++n) {
      const int r_loc = dir ? (31 - (16 * n + n16)) : (16 * n + n16);
#pragma unroll
      for (int tk = 0; tk < 2; ++tk) {
        const int base_dw = r_loc * 64 + 32 * tk + 8 * q;
        const float4 fa = *(const float4*)&stg[swz(base_dw)];
        const float4 fb = *(const float4*)&stg[swz(base_dw + 4)];
        Bf[n][tk] = to_h8(fa, fb);
      }
    }
#pragma unroll
    for (int n = 0; n < 2; ++n) {
      const int t_loc = 16 * n + n16;
      unsigned* wbase = &xcomp[t_loc * 68];
#pragma unroll
      for (int m = 0; m < 8; ++m) {
        f32x4 Cq = __builtin_amdgcn_mfma_f32_16x16x32_f16(AW[m][0], Bf[n][0], zeroq, 0, 0, 0);
        Cq = __builtin_amdgcn_mfma_f32_16x16x32_f16(AW[m][1], Bf[n][1], Cq, 0, 0, 0);
        uint2 pw;
        pw.x = pk16(Cq[0], Cq[1]);  // j = 16m+4q, 16m+4q+1
        pw.y = pk16(Cq[2], Cq[3]);  // j = 16m+4q+2, +3
        *(uint2*)(wbase + 8 * m + 2 * q) = pw;
      }
    }
  };

  // ---- staging: raw inputs chunks (contiguous both dirs; reversal in buildx) ----
  const char* islab = (const char*)(inputs + (size_t)b * kS * kD);
  const int c0off = dir ? 992 : 0;  // global row of chunk c: dir ? 992-32c : 32c
  stage_chunk_sw(islab + (size_t)(dir ? c0off : 0) * 256, (unsigned*)&instage[0][0], L);
  stage_chunk_sw(islab + (size_t)(dir ? (c0off - 32) : 32) * 256, (unsigned*)&instage[1][0], L);
  asm volatile("s_waitcnt vmcnt(8)" ::: "memory");  // chunk 0 staged
  buildx(&instage[0][0]);

  for (int c = 0; c < 32; ++c) {
    // ---- 32 recurrence steps on xcomp (R7-identical core) ----
#pragma unroll 2
    for (int s = 0; s < 32; ++s) {
      const unsigned xdw = xcomp[s * 68 + L];  // packed (x[2L], x[2L+1])
      float a0 = 0.f, a1 = 0.f, c0 = 0.f, c1 = 0.f;

      unsigned hb[32];
#pragma unroll
      for (int k = 0; k < 32; ++k) hb[k] = bcast(hcur, k);
#pragma unroll
      for (int k = 0; k < 32; ++k) {
        a0 = fdot2(w0[k], hb[k], a0);
        c0 = fdot2(w1[k], hb[k], c0);
      }
#pragma unroll
      for (int k = 0; k < 32; ++k) hb[k] = bcast(hcur, 32 + k);
#pragma unroll
      for (int k = 0; k < 32; ++k) {
        a1 = fdot2(w0[32 + k], hb[k], a1);
        c1 = fdot2(w1[32 + k], hb[k], c1);
      }

      const half2v xh = __builtin_bit_cast(half2v, xdw);
      const float va = (a0 + a1) + ((float)xh.x + bj0);
      const float vb = (c0 + c1) + ((float)xh.y + bj1);
      hcur = pk16(fast_tanh(va), fast_tanh(vb));
      jrn[s * 68 + L] = hcur;  // journal only; read at fc drain
    }

    // ---- stage chunk c+2; build xcomp for c+1 BEFORE the fc drain so the
    //      MFMA drain overlaps the drain's VALU/LDS work ----
    if (c < 30) {
      const int g2 = dir ? (c0off - 32 * (c + 2)) : 32 * (c + 2);
      stage_chunk_sw(islab + (size_t)g2 * 256, (unsigned*)&instage[c & 1][0], L);
      asm volatile("s_waitcnt vmcnt(8)" ::: "memory");  // chunk c+1 resident
      buildx(&instage[(c + 1) & 1][0]);
    } else if (c == 30) {
      asm volatile("s_waitcnt vmcnt(0)" ::: "memory");
      buildx(&instage[1][0]);
    }

    // ---- fc drain of chunk c ----
    {
      const int tl = L >> 1, jh = L & 1;
      const uint4* rp = (const uint4*)&jrn[tl * 68 + jh * 32];
      const uint4* fp = (const uint4*)&fcwl[jh * 32];
      float acc = 0.f;
#pragma unroll
      for (int k = 0; k < 8; ++k) {
        const uint4 hv = rp[k];
        const uint4 fw = fp[k];
        acc = fdot2(fw.x, hv.x, acc);
        acc = fdot2(fw.y, hv.y, acc);
        acc = fdot2(fw.z, hv.z, acc);
        acc = fdot2(fw.w, hv.w, acc);
      }
      acc += lane_xor1(acc);
      if (jh == 0) outbuf[c * 32 + tl] = acc;
    }
  }

  // ---- emit: one atomic pass (fw adds fcb) ----
  const float fcb0 = (dir == 0) ? fcb[0] : 0.f;
#pragma unroll
  for (int k = 0; k < 16; ++k) {
    const int t = L + 64 * k;
    const int td = dir ? (kS - 1 - t) : t;
    atomicAdd(&out[(size_t)b * kS + td], outbuf[t] + fcb0);
  }
}

}  // namespace

extern "C" void kernel_launch(void* const* d_in, const int* in_sizes, int n_in,
                              void* d_out, int out_size, void* d_ws, size_t ws_size,
                              hipStream_t stream) {
  (void)in_sizes; (void)n_in; (void)d_ws; (void)ws_size;
  const float* inputs = (const float*)d_in[0];
  const float* Wih_fw = (const float*)d_in[1];
  const float* Whh_fw = (const float*)d_in[2];
  const float* bih_fw = (const float*)d_in[3];
  const float* bhh_fw = (const float*)d_in[4];
  const float* Wih_bw = (const float*)d_in[5];
  const float* Whh_bw = (const float*)d_in[6];
  const float* bih_bw = (const float*)d_in[7];
  const float* bhh_bw = (const float*)d_in[8];
  const float* fc_W   = (const float*)d_in[9];
  const float* fc_b   = (const float*)d_in[10];
  float* out = (float*)d_out;

  hipMemsetAsync(out, 0, (size_t)out_size * sizeof(float), stream);

  hipLaunchKernelGGL(birnn_fused_kernel, dim3(512), dim3(64), 0, stream,
                     inputs, Wih_fw, bih_fw, bhh_fw, Wih_bw, bih_bw, bhh_bw,
                     Whh_fw, Whh_bw, fc_W, fc_b, out);
}